// Round 1
// 1227.208 us; speedup vs baseline: 1.3573x; 1.3573x over previous
//
#include <hip/hip_runtime.h>

// LSTMStateEstimation: 2-layer LSTM (B=64,T=256,IN=128,H=512) + FC(512->64).
//
// r10 = r9's proven exchange primitives + three protocol cuts:
//  1. Per-producer MONOTONIC flags (store t+1; no fetch_add RMW fan-in).
//     Consumer polls 16+16 flag words with 32 lanes -> one coalesced load
//     round checks BOTH dependencies; all 4 waves poll (no wait-barrier).
//  2. LDS-staged h: each WG loads the 8KB h slot ONCE (2x16B coherent
//     loads/thread), XOR-swizzled into LDS, fragments via ds_read_b128.
//     Cuts MALL coherent-read traffic 8x (was 64/128KB per WG-step).
//  3. L0's x-part MFMAs hoisted ahead of the wait (cached xg, off-chain).
// Exchange primitive set UNCHANGED from r9 (r4/r5-validated):
//   h loads : global_load_dwordx4 sc0 sc1 + TIE   (now 2-4 per thread)
//   h stores: 8B relaxed agent atomic stores
//   flags   : relaxed agent 4B atomic store / relaxed agent poll loads
// Polls bounded (protocol bug -> visible wrong answer, never a dead GPU).

#define NB    64
#define SEQL  256
#define INF   128
#define HID   512
#define OUTN  64
#define NWG   256
#define NT    256
#define NCNT  32
#define CADD  (NWG / NCNT)
#define PBOUND 4096

typedef __attribute__((ext_vector_type(8))) short  short8;
typedef __attribute__((ext_vector_type(4))) float  floatx4;
typedef unsigned short u16;
typedef unsigned long long u64;

#define TIE2(N, x0,x1)                                                      \
  asm volatile("s_waitcnt vmcnt(" N ")" : "+v"(x0), "+v"(x1))
#define TIE4(N, x0,x1,x2,x3)                                                \
  asm volatile("s_waitcnt vmcnt(" N ")" : "+v"(x0), "+v"(x1), "+v"(x2), "+v"(x3))

#define MFMA(ACC, A, B) \
  ACC = __builtin_amdgcn_mfma_f32_16x16x32_bf16((A), (B), ACC, 0, 0, 0)

__device__ __forceinline__ u16 f2bf(float f) {
  union { float f; unsigned u; } v; v.f = f;
  return (u16)((v.u + 0x7FFFu + ((v.u >> 16) & 1u)) >> 16);  // RNE
}
__device__ __forceinline__ float bf2f(u16 s) {
  union { unsigned u; float f; } v; v.u = ((unsigned)s) << 16;
  return v.f;
}
__device__ __forceinline__ float sigf(float v) { return 1.f / (1.f + __expf(-v)); }
__device__ __forceinline__ float tanh_fast(float v) {
  float cv = fminf(fmaxf(v, -15.f), 15.f);
  float e = __expf(2.f * cv);
  return (e - 1.f) / (e + 1.f);
}

// ---- proven exchange primitives (r4/r5-validated on MI355X) ----
__device__ __forceinline__ short8 ldh(const u16* p) {
  short8 d;
  asm volatile("global_load_dwordx4 %0, %1, off sc0 sc1" : "=v"(d) : "v"(p));
  return d;
}
__device__ __forceinline__ void st8c(u16* p, u64 v) {
  __hip_atomic_store((u64*)p, v, __ATOMIC_RELAXED, __HIP_MEMORY_SCOPE_AGENT);
}

// Per-producer flag wait: lanes 0-15 poll f0[0..15] vs thr0, lanes 16-31
// poll f1[0..15] vs thr1 (thr<=0 => vacuous). ALL waves call this; no
// barrier inside. Bounded. Ends with a compiler memory fence so the
// following staged ldh() asm cannot hoist above the poll.
__device__ __forceinline__ void wait_ge(const unsigned* f0, int thr0,
                                        const unsigned* f1, int thr1) {
  const int lane = threadIdx.x & 63;
  const unsigned* fp = nullptr;
  int thr = 0;
  if (lane < 16)      { fp = f0 + lane;        thr = thr0; }
  else if (lane < 32) { fp = f1 + (lane - 16); thr = thr1; }
  if (thr <= 0) fp = nullptr;
  for (int i = 0; i < PBOUND; ++i) {
    int v = 0x7fffffff;
    if (fp) v = (int)__hip_atomic_load(fp, __ATOMIC_RELAXED,
                                       __HIP_MEMORY_SCOPE_AGENT);
    if (__all(v >= thr)) break;
    if (i > 24) __builtin_amdgcn_s_sleep(1);
  }
  __builtin_amdgcn_sched_barrier(0);
  asm volatile("" ::: "memory");
}

// One-time MALL grid barrier (r5-proven shape), bounded poll.
__device__ __forceinline__ void grid_bar_once(unsigned* leaf, int w) {
  asm volatile("s_waitcnt vmcnt(0)" ::: "memory");
  __syncthreads();
  if (threadIdx.x == 0)
    __hip_atomic_fetch_add(&leaf[(w & (NCNT - 1)) * 32], 1u, __ATOMIC_RELAXED,
                           __HIP_MEMORY_SCOPE_AGENT);
  if (threadIdx.x < 64) {
    const int lane = threadIdx.x & 63;
    for (int i = 0; i < (1 << 16); ++i) {
      unsigned v = CADD;
      if (lane < NCNT)
        v = __hip_atomic_load(&leaf[lane * 32], __ATOMIC_RELAXED,
                              __HIP_MEMORY_SCOPE_AGENT);
      if (__all(v >= CADD)) break;
      __builtin_amdgcn_s_sleep(1);
    }
  }
  __syncthreads();
}

// B-fragments: 2 n-tiles (rowid = wv*32 + t2*16 + mrow) x KS k-steps.
// rowid -> unit u = rowid>>2, gate G = rowid&3; gate-row r = G*512+32*li+u.
// K-layout = [input(KIN) | h_prev(512)].
template <int KS, int KIN>
__device__ __forceinline__ void load_B(short8 (&Bf)[2][32],
                                       const float* __restrict__ Wih,
                                       const float* __restrict__ Whh,
                                       int li, int wv, int mrow, int quad) {
#pragma unroll
  for (int t2 = 0; t2 < 2; ++t2) {
    const int rowid = wv * 32 + t2 * 16 + mrow;
    const int r = (rowid & 3) * HID + 32 * li + (rowid >> 2);
    const float* wr = Wih + (size_t)r * KIN;
    const float* hr = Whh + (size_t)r * HID - KIN;   // hr[k]=Whh[r][k-KIN]
#pragma unroll
    for (int ks = 0; ks < KS; ++ks) {
      short8 v;
#pragma unroll
      for (int j = 0; j < 8; ++j) {
        const int k = 32 * ks + quad * 8 + j;
        v[j] = (short)f2bf(k < KIN ? wr[k] : hr[k]);
      }
      Bf[t2][ks] = v;
    }
  }
}

__global__ __launch_bounds__(NT, 1) void lstm_groups(
    const float* __restrict__ x,
    const float* __restrict__ Wih0, const float* __restrict__ Whh0,
    const float* __restrict__ bih0, const float* __restrict__ bhh0,
    const float* __restrict__ Wih1, const float* __restrict__ Whh1,
    const float* __restrict__ bih1, const float* __restrict__ bhh1,
    const float* __restrict__ Wfc,  const float* __restrict__ bfc,
    float* __restrict__ out,
    unsigned* __restrict__ leaf,
    unsigned* __restrict__ flag0, unsigned* __restrict__ flag1,
    u16* __restrict__ h0r, u16* __restrict__ h1r, u16* __restrict__ xg)
{
  const int w = blockIdx.x, tid = threadIdx.x;
  const int lane = tid & 63, wv = tid >> 6;
  const int quad = lane >> 4, mrow = lane & 15;
  const int g = w & 7, m = w >> 3;          // group, member (0..31)
  const bool isL1 = (m >= 16);
  const int  li   = isL1 ? m - 16 : m;      // layer-local WG index (0..15)

  __shared__ float g_lds[128][9];
  __shared__ u64   h_lds8[8][8];
  __shared__ float bias_lds[128];
  __shared__ float red[16][17];
  // h staging: [b(8)][k(512)] bf16 = 8KB, XOR-swizzled: byte ^= (b&7)<<4.
  __shared__ short8 hA[512];
  __shared__ short8 hB[512];
  char* hAc = (char*)hA;
  char* hBc = (char*)hB;

  // ---- xg fill: xg[g][t][b][k] bf16, 8 (g,t)-slices per WG, MALL stores ----
#pragma unroll
  for (int i = 0; i < 8; ++i) {
    const int s = w * 8 + i, gs = s >> 8, ts = s & 255;
    u16* dst = xg + (size_t)(gs * 256 + ts) * 1024;
    const int b = tid >> 5, k0 = (tid & 31) * 4;
    const float* src = x + ((size_t)(8 * gs + b) * SEQL + ts) * INF + k0;
    union { u16 h[4]; u64 u; } pk;
#pragma unroll
    for (int j = 0; j < 4; ++j) pk.h[j] = f2bf(src[j]);
    st8c(dst + b * 128 + k0, pk.u);
  }

  // ---- weights -> VGPR B-fragments; bias -> LDS ----
  short8 Bf[2][32];
  if (isL1) load_B<32, HID>(Bf, Wih1, Whh1, li, wv, mrow, quad);
  else      load_B<20, INF>(Bf, Wih0, Whh0, li, wv, mrow, quad);
  if (tid < 128) {
    const int r = (tid & 3) * HID + 32 * li + (tid >> 2);
    bias_lds[tid] = (isL1 ? bih1[r] + bhh1[r] : bih0[r] + bhh0[r]);
  }

  grid_bar_once(leaf, w);   // xg complete everywhere; rings/flags zeroed

  // per-producer flags: flag[g*64 + p], p = producer li (monotonic t+1)
  unsigned* flag0g = flag0 + g * 64;
  unsigned* flag1g = flag1 + g * 64;
  u16* h0g = h0r + (size_t)g * 32768;       // 8 slots x 8 b x 512 k
  u16* h1g = h1r + (size_t)g * 32768;
  const u16* xgg = xg + (size_t)g * 256 * 1024;

  float cst = 0.f;                 // fp32 cell state, thread-private
  const int ab = mrow & 7;         // batch of this lane's A row (dup 8..15)
  const int koff = quad * 8;

  // staging LDS offsets for this thread (granule tid and tid+256)
  const int so0 = (tid * 16) ^ ((tid >> 6) << 4);
  const int so1 = ((tid + 256) * 16) ^ (((tid + 256) >> 6) << 4);

  for (int t = 0; t < SEQL; ++t) {
    floatx4 a00 = {0,0,0,0}, a01 = {0,0,0,0}, a10 = {0,0,0,0}, a11 = {0,0,0,0};

    if (!isL1) {
      // ---- x-part first: cached xg loads, independent of flags ----
      const u16* xa = xgg + (size_t)t * 1024 + ab * 128 + koff;
      short8 x0 = *(const short8*)(xa +  0);
      short8 x1 = *(const short8*)(xa + 32);
      short8 x2 = *(const short8*)(xa + 64);
      short8 x3 = *(const short8*)(xa + 96);
      MFMA(a00,x0,Bf[0][0]);  MFMA(a10,x0,Bf[1][0]);
      MFMA(a01,x1,Bf[0][1]);  MFMA(a11,x1,Bf[1][1]);
      MFMA(a00,x2,Bf[0][2]);  MFMA(a10,x2,Bf[1][2]);
      MFMA(a01,x3,Bf[0][3]);  MFMA(a11,x3,Bf[1][3]);

      // peers done t-1 (flag>=t); L1 consumed h0[t-8] (flag1>=t-7, ring WAR)
      wait_ge(flag0g, t, flag1g, t - 7);

      // ---- stage h0_{t-1} (8KB) once per WG into swizzled LDS ----
      const u16* src = h0g + ((t + 7) & 7) * 4096;
      short8 s0 = ldh(src + tid * 8);
      short8 s1 = ldh(src + (tid + 256) * 8);
      TIE2("0", s0, s1);
      *(short8*)(hAc + so0) = s0;
      *(short8*)(hAc + so1) = s1;
      __syncthreads();

#pragma unroll
      for (int n = 0; n < 16; ++n) {
        const short8 fv = *(const short8*)(
            hAc + ((ab * 1024 + n * 64 + quad * 16) ^ (ab << 4)));
        if ((n & 1) == 0) { MFMA(a00, fv, Bf[0][4 + n]); MFMA(a10, fv, Bf[1][4 + n]); }
        else              { MFMA(a01, fv, Bf[0][4 + n]); MFMA(a11, fv, Bf[1][4 + n]); }
      }
    } else {
      // L0 done t (flag0>=t+1); peers done t-1 (flag1>=t, also h1-ring safe)
      wait_ge(flag0g, t + 1, flag1g, t);

      // ---- stage h0_t and h1_{t-1} (8KB each) into swizzled LDS ----
      const u16* srcA = h0g + (t & 7) * 4096;
      const u16* srcB = h1g + ((t + 7) & 7) * 4096;
      short8 sa0 = ldh(srcA + tid * 8);
      short8 sa1 = ldh(srcA + (tid + 256) * 8);
      short8 sb0 = ldh(srcB + tid * 8);
      short8 sb1 = ldh(srcB + (tid + 256) * 8);
      TIE4("0", sa0, sa1, sb0, sb1);
      *(short8*)(hAc + so0) = sa0;
      *(short8*)(hAc + so1) = sa1;
      *(short8*)(hBc + so0) = sb0;
      *(short8*)(hBc + so1) = sb1;
      __syncthreads();

#pragma unroll
      for (int n = 0; n < 32; ++n) {
        const char* P = (n < 16) ? hAc : hBc;
        const int nn = n & 15;
        const short8 fv = *(const short8*)(
            P + ((ab * 1024 + nn * 64 + quad * 16) ^ (ab << 4)));
        if ((n & 1) == 0) { MFMA(a00, fv, Bf[0][n]); MFMA(a10, fv, Bf[1][n]); }
        else              { MFMA(a01, fv, Bf[0][n]); MFMA(a11, fv, Bf[1][n]); }
      }
    }

    const floatx4 accA = a00 + a01, accB = a10 + a11;
    // D layout: col(lane&15)->rowid-in-tile, row(quad*4+reg)->batch (0-7 real)
    if (quad < 2) {
#pragma unroll
      for (int r = 0; r < 4; ++r) {
        g_lds[wv * 32 + mrow][quad * 4 + r]      = accA[r];
        g_lds[wv * 32 + 16 + mrow][quad * 4 + r] = accB[r];
      }
    }
    __syncthreads();

    {  // gate math: thread -> (batch b, unit u); c stays in a register
      const int u = tid & 31, b = tid >> 5;
      const float gi = g_lds[u * 4 + 0][b] + bias_lds[u * 4 + 0];
      const float gf = g_lds[u * 4 + 1][b] + bias_lds[u * 4 + 1];
      const float gg = g_lds[u * 4 + 2][b] + bias_lds[u * 4 + 2];
      const float go = g_lds[u * 4 + 3][b] + bias_lds[u * 4 + 3];
      const float c = sigf(gf) * cst + sigf(gi) * tanh_fast(gg);
      cst = c;
      ((u16*)&h_lds8[b][0])[u] = f2bf(sigf(go) * tanh_fast(c));
    }
    __syncthreads();

    if (tid < 64) {   // 8B MALL-coherent stores: 4 units each
      const int b = tid >> 3, u8 = tid & 7;
      const u64 v = h_lds8[b][u8];
      u16* dst = (isL1 ? h1g : h0g) + (t & 7) * 4096 + b * 512 + li * 32 + u8 * 4;
      st8c(dst, v);
    }
    asm volatile("s_waitcnt vmcnt(0)" ::: "memory");   // h in MALL before flag
    if (tid == 0)
      __hip_atomic_store((isL1 ? flag1g : flag0g) + li, (unsigned)(t + 1),
                         __ATOMIC_RELAXED, __HIP_MEMORY_SCOPE_AGENT);
  }

  // ---- FC head: out[b][o] = h1_255[b] . Wfc[o] + bfc[o] ----
  wait_ge(flag1g, 256, flag1g, 256);   // all L1 producers done t=255
  {
    const int bloc = m >> 2, oq = m & 3;    // 32 members = 8 b x 4 o-blocks
    const int ol = tid >> 4, ksub = tid & 15;
    const u16* hp = h1g + 7 * 4096 + bloc * 512 + ksub * 32;
    short8 v0 = ldh(hp),      v1 = ldh(hp + 8);
    short8 v2 = ldh(hp + 16), v3 = ldh(hp + 24);
    TIE4("0", v0, v1, v2, v3);
    const float* wr = Wfc + (size_t)(oq * 16 + ol) * HID + ksub * 32;
    float s = 0.f;
#pragma unroll
    for (int j = 0; j < 8; ++j) {
      s += bf2f((u16)v0[j]) * wr[j];
      s += bf2f((u16)v1[j]) * wr[8 + j];
      s += bf2f((u16)v2[j]) * wr[16 + j];
      s += bf2f((u16)v3[j]) * wr[24 + j];
    }
    red[ol][ksub] = s;
    __syncthreads();
    if (tid < 16) {
      float sum = 0.f;
#pragma unroll
      for (int j = 0; j < 16; ++j) sum += red[tid][j];
      out[(size_t)(8 * g + bloc) * OUTN + oq * 16 + tid] = sum + bfc[oq * 16 + tid];
    }
  }
}

// Workspace layout (bytes):
//   [256, 4352)          one-time barrier leaves (32 x 128B)
//   [8192, 10240)        flag0[8][64] u32 (per-producer monotonic, 16 used)
//   [16384, 18432)       flag1[8][64] u32
//   [32768, 557056)      h0 rings: 8 groups x 8 slots x 8 b x 512 k bf16
//   [557056, 1081344)    h1 rings
//   [1081344, 5275648)   xg: 8 groups x 256 t x 8 b x 128 k bf16
// memset [0, 1081344) each launch (flags/rings; slot 7 = h[-1] = 0).

extern "C" void kernel_launch(void* const* d_in, const int* in_sizes, int n_in,
                              void* d_out, int out_size, void* d_ws, size_t ws_size,
                              hipStream_t stream) {
  (void)in_sizes; (void)n_in; (void)out_size; (void)ws_size;

  char* ws = (char*)d_ws;
  unsigned* leaf  = (unsigned*)(ws + 256);
  unsigned* flag0 = (unsigned*)(ws + 8192);
  unsigned* flag1 = (unsigned*)(ws + 16384);
  u16* h0r = (u16*)(ws + 32768);
  u16* h1r = (u16*)(ws + 557056);
  u16* xg  = (u16*)(ws + 1081344);

  hipMemsetAsync(d_ws, 0, 1081344, stream);

  const float* x    = (const float*)d_in[0];
  const float* Wih0 = (const float*)d_in[1];
  const float* Whh0 = (const float*)d_in[2];
  const float* bih0 = (const float*)d_in[3];
  const float* bhh0 = (const float*)d_in[4];
  const float* Wih1 = (const float*)d_in[5];
  const float* Whh1 = (const float*)d_in[6];
  const float* bih1 = (const float*)d_in[7];
  const float* bhh1 = (const float*)d_in[8];
  const float* Wfc  = (const float*)d_in[9];
  const float* bfc  = (const float*)d_in[10];
  float* out = (float*)d_out;

  void* args[] = {
    (void*)&x,
    (void*)&Wih0, (void*)&Whh0, (void*)&bih0, (void*)&bhh0,
    (void*)&Wih1, (void*)&Whh1, (void*)&bih1, (void*)&bhh1,
    (void*)&Wfc,  (void*)&bfc,
    (void*)&out,
    (void*)&leaf, (void*)&flag0, (void*)&flag1,
    (void*)&h0r, (void*)&h1r, (void*)&xg
  };
  hipError_t err = hipLaunchCooperativeKernel((const void*)lstm_groups,
                                              dim3(NWG), dim3(NT), args, 0, stream);
  if (err != hipSuccess) {
    // 256 blocks @ 1 block/CU on 256 CUs are co-resident structurally.
    hipLaunchKernelGGL(lstm_groups, dim3(NWG), dim3(NT), 0, stream,
                       x, Wih0, Whh0, bih0, bhh0, Wih1, Whh1, bih1, bhh1,
                       Wfc, bfc, out, leaf, flag0, flag1, h0r, h1r, xg);
  }
}